// Round 1
// baseline (192.880 us; speedup 1.0000x reference)
//
#include <hip/hip_runtime.h>
#include <math.h>

#pragma clang fp contract(off)

#define NUM_PRIORS 72192
#define BATCH      64
#define TOPK       200
#define CONF_TH    0.01f
#define NMS_TH     0.45f
#define NBINS      256
#define SLICES     16
#define CAP        1024
#define KEEPW      7   // ceil(200/32)

// ---- binning: monotonic map score -> bin, identical in both kernels ----
__device__ __forceinline__ int bin_of(float s) {
    int b = (int)(s * 256.0f);
    return b > 255 ? 255 : b;
}

// ---------------- kernel 1: per-batch score histogram ----------------
__global__ void hist_kernel(const float* __restrict__ conf, unsigned* __restrict__ ghist) {
    __shared__ unsigned lhist[NBINS];
    const int b = blockIdx.y, slice = blockIdx.x, tid = threadIdx.x;
    for (int i = tid; i < NBINS; i += blockDim.x) lhist[i] = 0;
    __syncthreads();
    const int rows = NUM_PRIORS / SLICES;       // 4512
    const int q4   = rows / 2;                  // 2256 float4 (2 rows each)
    const float4* c4 = (const float4*)conf;
    const long base4 = ((long)b * NUM_PRIORS + (long)slice * rows) / 2;
    for (int q = tid; q < q4; q += blockDim.x) {
        float4 v = c4[base4 + q];
        if (v.y > CONF_TH) atomicAdd(&lhist[bin_of(v.y)], 1u);
        if (v.w > CONF_TH) atomicAdd(&lhist[bin_of(v.w)], 1u);
    }
    __syncthreads();
    for (int i = tid; i < NBINS; i += blockDim.x) {
        unsigned v = lhist[i];
        if (v) atomicAdd(&ghist[b * NBINS + i], v);
    }
}

// ------- kernel 2: find threshold bin, collect candidate keys -------
__global__ void collect_kernel(const float* __restrict__ conf,
                               const unsigned* __restrict__ ghist,
                               unsigned* __restrict__ cnt,
                               unsigned long long* __restrict__ cand) {
    __shared__ unsigned suf[NBINS];
    __shared__ int Tsh;
    const int b = blockIdx.y, slice = blockIdx.x, tid = threadIdx.x;
    if (tid < NBINS) suf[tid] = ghist[b * NBINS + tid];
    if (tid == 0) Tsh = 0;
    __syncthreads();
    // suffix sum (Hillis-Steele)
    for (int off = 1; off < NBINS; off <<= 1) {
        unsigned v = (tid + off < NBINS) ? suf[tid + off] : 0u;
        __syncthreads();
        if (tid < NBINS) suf[tid] += v;
        __syncthreads();
    }
    if (tid < NBINS) {
        unsigned s = suf[tid];
        unsigned sn = (tid + 1 < NBINS) ? suf[tid + 1] : 0u;
        if (s >= TOPK && (tid == NBINS - 1 || sn < TOPK)) Tsh = tid;
    }
    __syncthreads();
    const int T = Tsh;   // if total valid < TOPK: no writer -> T=0 (take all)

    const int rows = NUM_PRIORS / SLICES;
    const int q4   = rows / 2;
    const float4* c4 = (const float4*)conf;
    const long base4 = ((long)b * NUM_PRIORS + (long)slice * rows) / 2;
    const int prow0 = slice * rows;
    for (int q = tid; q < q4; q += blockDim.x) {
        float4 v = c4[base4 + q];
        int p0 = prow0 + 2 * q, p1 = p0 + 1;
        if (v.y > CONF_TH && bin_of(v.y) >= T) {
            unsigned pos = atomicAdd(&cnt[b], 1u);
            if (pos < CAP)
                cand[(long)b * CAP + pos] =
                    ((unsigned long long)__float_as_uint(v.y) << 32) |
                    (unsigned long long)(0xFFFFFFFFu - (unsigned)p0);
        }
        if (v.w > CONF_TH && bin_of(v.w) >= T) {
            unsigned pos = atomicAdd(&cnt[b], 1u);
            if (pos < CAP)
                cand[(long)b * CAP + pos] =
                    ((unsigned long long)__float_as_uint(v.w) << 32) |
                    (unsigned long long)(0xFFFFFFFFu - (unsigned)p1);
        }
    }
}

// ------- kernel 3: sort, decode, NMS, compact, write -------
__global__ void nms_kernel(const float* __restrict__ loc,
                           const float* __restrict__ prior,
                           const unsigned* __restrict__ cnt,
                           const unsigned long long* __restrict__ cand,
                           float* __restrict__ out) {
    __shared__ unsigned long long keys[CAP];
    __shared__ float bx1[TOPK], by1[TOPK], bx2[TOPK], by2[TOPK], bsc[TOPK], bar[TOPK];
    __shared__ unsigned sup[TOPK][KEEPW];
    __shared__ unsigned kw[KEEPW];
    __shared__ unsigned char vld[TOPK];
    const int b = blockIdx.x, tid = threadIdx.x;
    const unsigned n0 = cnt[b];
    const int n = (n0 < CAP) ? (int)n0 : CAP;

    for (int i = tid; i < CAP; i += blockDim.x)
        keys[i] = (i < n) ? cand[(long)b * CAP + i] : 0ull;
    __syncthreads();

    // bitonic sort, descending
    for (unsigned k = 2; k <= CAP; k <<= 1) {
        for (unsigned j = k >> 1; j > 0; j >>= 1) {
            for (unsigned i = tid; i < CAP; i += blockDim.x) {
                unsigned l = i ^ j;
                if (l > i) {
                    unsigned long long a = keys[i], c = keys[l];
                    bool ascBlock = ((i & k) == 0);
                    bool doswap = ascBlock ? (a < c) : (a > c);
                    if (doswap) { keys[i] = c; keys[l] = a; }
                }
            }
            __syncthreads();
        }
    }

    // decode top-200
    if (tid < TOPK) {
        unsigned long long key = keys[tid];
        float s = __uint_as_float((unsigned)(key >> 32));
        unsigned p = 0xFFFFFFFFu - (unsigned)(key & 0xFFFFFFFFull);
        bool valid = (tid < n) && (s > CONF_TH);
        float x1 = 0.f, y1 = 0.f, x2 = 0.f, y2 = 0.f;
        if (valid) {
            float4 l4 = ((const float4*)loc)[(long)b * NUM_PRIORS + p];
            float4 p4 = ((const float4*)prior)[p];
            // match reference op order exactly (contract off)
            float cx = p4.x + (l4.x * 0.1f) * p4.z;
            float cy = p4.y + (l4.y * 0.1f) * p4.w;
            float w  = p4.z * (float)exp((double)(l4.z * 0.2f));
            float h  = p4.w * (float)exp((double)(l4.w * 0.2f));
            x1 = cx - w * 0.5f; y1 = cy - h * 0.5f;
            x2 = cx + w * 0.5f; y2 = cy + h * 0.5f;
        }
        bsc[tid] = valid ? s : 0.f;
        bx1[tid] = x1; by1[tid] = y1; bx2[tid] = x2; by2[tid] = y2;
        bar[tid] = (x2 - x1) * (y2 - y1);
        vld[tid] = valid ? 1 : 0;
    }
    for (int i = tid; i < TOPK * KEEPW; i += blockDim.x)
        ((unsigned*)sup)[i] = 0u;
    __syncthreads();

    // pairwise suppression bits (i < j only; iou is symmetric bit-exactly)
    for (int kk = tid; kk < TOPK * TOPK; kk += blockDim.x) {
        int i = kk / TOPK, j = kk % TOPK;
        if (j <= i) continue;
        float ltx = fmaxf(bx1[i], bx1[j]);
        float lty = fmaxf(by1[i], by1[j]);
        float rbx = fminf(bx2[i], bx2[j]);
        float rby = fminf(by2[i], by2[j]);
        float wx = fmaxf(rbx - ltx, 0.0f);
        float wy = fmaxf(rby - lty, 0.0f);
        float inter = wx * wy;
        float uni = (bar[i] + bar[j]) - inter;
        float iou = inter / fmaxf(uni, 1e-12f);
        if (iou > NMS_TH) atomicOr(&sup[i][j >> 5], 1u << (j & 31));
    }
    __syncthreads();

    // serial greedy resolve (cheap: 200 iters of 7-word ANDs)
    if (tid == 0) {
        unsigned k0[KEEPW];
        for (int w = 0; w < KEEPW; w++) k0[w] = 0u;
        for (int i = 0; i < TOPK; i++)
            if (vld[i]) k0[i >> 5] |= 1u << (i & 31);
        for (int i = 0; i < TOPK; i++) {
            if ((k0[i >> 5] >> (i & 31)) & 1u) {
                for (int w = 0; w < KEEPW; w++) k0[w] &= ~sup[i][w];
            }
        }
        for (int w = 0; w < KEEPW; w++) kw[w] = k0[w];
    }
    __syncthreads();

    // compact + write (out pre-zeroed)
    if (tid < TOPK) {
        bool keep = (kw[tid >> 5] >> (tid & 31)) & 1u;
        if (keep) {
            int pos = 0;
            for (int w = 0; w < (tid >> 5); w++) pos += __popc(kw[w]);
            pos += __popc(kw[tid >> 5] & ((1u << (tid & 31)) - 1u));
            float* o = out + (((long)b * 2 + 1) * TOPK + pos) * 5;
            o[0] = bsc[tid];
            o[1] = bx1[tid];
            o[2] = by1[tid];
            o[3] = bx2[tid];
            o[4] = by2[tid];
        }
    }
}

extern "C" void kernel_launch(void* const* d_in, const int* in_sizes, int n_in,
                              void* d_out, int out_size, void* d_ws, size_t ws_size,
                              hipStream_t stream) {
    const float* loc   = (const float*)d_in[0];   // [64, 72192, 4]
    const float* conf  = (const float*)d_in[1];   // [64*72192, 2]
    const float* prior = (const float*)d_in[2];   // [72192, 4]
    float* out = (float*)d_out;                   // [64, 2, 200, 5]

    unsigned* ghist = (unsigned*)d_ws;                                  // 64*256 u32 = 65536 B
    unsigned* cnt   = ghist + BATCH * NBINS;                            // 64 u32  (ends 65792)
    unsigned long long* cand =
        (unsigned long long*)((char*)d_ws + 65792);                     // 64*1024 u64 = 512 KiB

    hipMemsetAsync(d_out, 0, (size_t)out_size * sizeof(float), stream);
    hipMemsetAsync(d_ws, 0, 65792, stream);

    hist_kernel<<<dim3(SLICES, BATCH), 256, 0, stream>>>(conf, ghist);
    collect_kernel<<<dim3(SLICES, BATCH), 256, 0, stream>>>(conf, ghist, cnt, cand);
    nms_kernel<<<BATCH, 256, 0, stream>>>(loc, prior, cnt, cand, out);
}

// Round 2
// 145.694 us; speedup vs baseline: 1.3239x; 1.3239x over previous
//
#include <hip/hip_runtime.h>
#include <math.h>

#pragma clang fp contract(off)

#define NUM_PRIORS 72192
#define BATCH      64
#define TOPK       200
#define CONF_TH    0.01f
#define NMS_TH     0.45f
#define NBINS      256
#define SLICES     16
#define CAP        1024
#define SUPW       7   // ceil(200/32)

// ---- binning: monotonic map score -> bin, identical in both kernels ----
__device__ __forceinline__ int bin_of(float s) {
    int b = (int)(s * 256.0f);
    return b > 255 ? 255 : b;
}

// ---------------- kernel 1: per-batch score histogram ----------------
__global__ void hist_kernel(const float* __restrict__ conf, unsigned* __restrict__ ghist) {
    __shared__ unsigned lhist[NBINS];
    const int b = blockIdx.y, slice = blockIdx.x, tid = threadIdx.x;
    for (int i = tid; i < NBINS; i += blockDim.x) lhist[i] = 0;
    __syncthreads();
    const int rows = NUM_PRIORS / SLICES;       // 4512
    const int q4   = rows / 2;                  // 2256 float4 (2 rows each)
    const float4* c4 = (const float4*)conf;
    const long base4 = ((long)b * NUM_PRIORS + (long)slice * rows) / 2;
    for (int q = tid; q < q4; q += blockDim.x) {
        float4 v = c4[base4 + q];
        if (v.y > CONF_TH) atomicAdd(&lhist[bin_of(v.y)], 1u);
        if (v.w > CONF_TH) atomicAdd(&lhist[bin_of(v.w)], 1u);
    }
    __syncthreads();
    for (int i = tid; i < NBINS; i += blockDim.x) {
        unsigned v = lhist[i];
        if (v) atomicAdd(&ghist[b * NBINS + i], v);
    }
}

// ------- kernel 2: find threshold bin, collect candidate keys -------
__global__ void collect_kernel(const float* __restrict__ conf,
                               const unsigned* __restrict__ ghist,
                               unsigned* __restrict__ cnt,
                               unsigned long long* __restrict__ cand) {
    __shared__ unsigned suf[NBINS];
    __shared__ int Tsh;
    const int b = blockIdx.y, slice = blockIdx.x, tid = threadIdx.x;
    if (tid < NBINS) suf[tid] = ghist[b * NBINS + tid];
    if (tid == 0) Tsh = 0;
    __syncthreads();
    // suffix sum (Hillis-Steele)
    for (int off = 1; off < NBINS; off <<= 1) {
        unsigned v = (tid + off < NBINS) ? suf[tid + off] : 0u;
        __syncthreads();
        if (tid < NBINS) suf[tid] += v;
        __syncthreads();
    }
    if (tid < NBINS) {
        unsigned s = suf[tid];
        unsigned sn = (tid + 1 < NBINS) ? suf[tid + 1] : 0u;
        if (s >= TOPK && (tid == NBINS - 1 || sn < TOPK)) Tsh = tid;
    }
    __syncthreads();
    const int T = Tsh;   // if total valid < TOPK: no writer -> T=0 (take all)

    const int rows = NUM_PRIORS / SLICES;
    const int q4   = rows / 2;
    const float4* c4 = (const float4*)conf;
    const long base4 = ((long)b * NUM_PRIORS + (long)slice * rows) / 2;
    const int prow0 = slice * rows;
    for (int q = tid; q < q4; q += blockDim.x) {
        float4 v = c4[base4 + q];
        int p0 = prow0 + 2 * q, p1 = p0 + 1;
        if (v.y > CONF_TH && bin_of(v.y) >= T) {
            unsigned pos = atomicAdd(&cnt[b], 1u);
            if (pos < CAP)
                cand[(long)b * CAP + pos] =
                    ((unsigned long long)__float_as_uint(v.y) << 32) |
                    (unsigned long long)(0xFFFFFFFFu - (unsigned)p0);
        }
        if (v.w > CONF_TH && bin_of(v.w) >= T) {
            unsigned pos = atomicAdd(&cnt[b], 1u);
            if (pos < CAP)
                cand[(long)b * CAP + pos] =
                    ((unsigned long long)__float_as_uint(v.w) << 32) |
                    (unsigned long long)(0xFFFFFFFFu - (unsigned)p1);
        }
    }
}

// ------- kernel 3: rank-sort, decode, NMS (ballot greedy), compact, write -------
__global__ __launch_bounds__(256) void nms_kernel(const float* __restrict__ loc,
                           const float* __restrict__ prior,
                           const unsigned* __restrict__ cnt,
                           const unsigned long long* __restrict__ cand,
                           float* __restrict__ out) {
    __shared__ unsigned long long keys[CAP];
    __shared__ float bx1[TOPK], by1[TOPK], bx2[TOPK], by2[TOPK], bsc[TOPK], bar[TOPK];
    __shared__ unsigned supT[TOPK][SUPW];   // column-major: bit i of supT[j] = sup(i->j)
    __shared__ unsigned long long keepw[4];
    __shared__ unsigned char vld[TOPK];
    const int b = blockIdx.x, tid = threadIdx.x;
    const unsigned n0 = cnt[b];
    const int n = (n0 < CAP) ? (int)n0 : CAP;

    // zero this batch's output region (replaces host-side memset of d_out)
    {
        float* ob = out + (long)b * 2 * TOPK * 5;
        for (int i = tid; i < 2 * TOPK * 5; i += 256) ob[i] = 0.f;
    }
    for (int i = tid; i < TOPK; i += 256) {
        bsc[i] = 0.f; bx1[i] = 0.f; by1[i] = 0.f; bx2[i] = 0.f; by2[i] = 0.f;
        bar[i] = 0.f; vld[i] = 0;
    }
    for (int i = tid; i < n; i += 256) keys[i] = cand[(long)b * CAP + i];
    __syncthreads();

    // ---- rank computation (exact top_k order: keys unique) + fused decode ----
    unsigned long long kc[4];
#pragma unroll
    for (int s = 0; s < 4; s++) {
        int c = tid + s * 256;
        kc[s] = (c < n) ? keys[c] : 0ull;
    }
    int rk[4] = {0, 0, 0, 0};
    for (int k = 0; k < n; k++) {
        unsigned long long kk = keys[k];   // broadcast read
#pragma unroll
        for (int s = 0; s < 4; s++) rk[s] += (kk > kc[s]) ? 1 : 0;
    }
#pragma unroll
    for (int s = 0; s < 4; s++) {
        int c = tid + s * 256;
        if (c < n && rk[s] < TOPK) {
            unsigned long long key = kc[s];
            float sc = __uint_as_float((unsigned)(key >> 32));
            unsigned p = 0xFFFFFFFFu - (unsigned)(key & 0xFFFFFFFFull);
            float4 l4 = ((const float4*)loc)[(long)b * NUM_PRIORS + p];
            float4 p4 = ((const float4*)prior)[p];
            // match reference op order exactly (contract off)
            float cx = p4.x + (l4.x * 0.1f) * p4.z;
            float cy = p4.y + (l4.y * 0.1f) * p4.w;
            float w_ = p4.z * (float)exp((double)(l4.z * 0.2f));
            float h_ = p4.w * (float)exp((double)(l4.w * 0.2f));
            float x1 = cx - w_ * 0.5f, y1 = cy - h_ * 0.5f;
            float x2 = cx + w_ * 0.5f, y2 = cy + h_ * 0.5f;
            int r = rk[s];
            bsc[r] = sc; bx1[r] = x1; by1[r] = y1; bx2[r] = x2; by2[r] = y2;
            bar[r] = (x2 - x1) * (y2 - y1);
            vld[r] = 1;
        }
    }
    __syncthreads();

    // ---- build column-major suppression bitmask (thread j owns column j) ----
    if (tid < TOPK) {
        const int j = tid;
        const float jx1 = bx1[j], jy1 = by1[j], jx2 = bx2[j], jy2 = by2[j], jar = bar[j];
#pragma unroll
        for (int w = 0; w < SUPW; w++) {
            unsigned bits = 0u;
            const int nb = (w == 6) ? 8 : 32;
            for (int t = 0; t < nb; t++) {
                const int i = w * 32 + t;
                if (i < j) {
                    float ltx = fmaxf(bx1[i], jx1);
                    float lty = fmaxf(by1[i], jy1);
                    float rbx = fminf(bx2[i], jx2);
                    float rby = fminf(by2[i], jy2);
                    float wx = fmaxf(rbx - ltx, 0.0f);
                    float wy = fmaxf(rby - lty, 0.0f);
                    float inter = wx * wy;
                    float uni = (bar[i] + jar) - inter;
                    float iou = inter / fmaxf(uni, 1e-12f);
                    if (iou > NMS_TH) bits |= 1u << t;
                }
            }
            supT[j][w] = bits;
        }
    }
    __syncthreads();

    // ---- greedy resolve: wave 0, all-register, ballot-based (no LDS in loop) ----
    if (tid < 64) {
        const int l = tid;
        unsigned c0[SUPW], c1[SUPW], c2[SUPW], c3[SUPW];
#pragma unroll
        for (int w = 0; w < SUPW; w++) {
            c0[w] = supT[l][w];
            c1[w] = supT[l + 64][w];
            c2[w] = supT[l + 128][w];
            c3[w] = (l < 8) ? supT[l + 192][w] : 0u;
        }
        unsigned long long k0 = __ballot(vld[l] != 0);
        unsigned long long k1 = __ballot(vld[l + 64] != 0);
        unsigned long long k2 = __ballot(vld[l + 128] != 0);
        unsigned long long k3 = __ballot((l < 8) && (vld[l + 192] != 0));
#pragma unroll
        for (int w = 0; w < SUPW; w++) {
            const int nb = (w == 6) ? 8 : 32;
            for (int t = 0; t < nb; t++) {
                unsigned long long m0 = __ballot(((c0[w] >> t) & 1u) != 0);
                unsigned long long m1 = __ballot(((c1[w] >> t) & 1u) != 0);
                unsigned long long m2 = __ballot(((c2[w] >> t) & 1u) != 0);
                unsigned long long m3 = __ballot(((c3[w] >> t) & 1u) != 0);
                const int slot = w >> 1;                     // static per w
                unsigned long long kw_ = (slot == 0) ? k0 : (slot == 1) ? k1
                                        : (slot == 2) ? k2 : k3;
                bool ki = (kw_ >> ((w & 1) * 32 + t)) & 1ull;
                if (ki) { k0 &= ~m0; k1 &= ~m1; k2 &= ~m2; k3 &= ~m3; }
            }
        }
        if (l == 0) { keepw[0] = k0; keepw[1] = k1; keepw[2] = k2; keepw[3] = k3; }
    }
    __syncthreads();

    // ---- compact + write kept rows ----
    if (tid < TOPK) {
        const int slot = tid >> 6, off = tid & 63;
        const unsigned long long kw_ = keepw[slot];
        if ((kw_ >> off) & 1ull) {
            int pos = 0;
            for (int s2 = 0; s2 < slot; s2++) pos += __popcll(keepw[s2]);
            pos += __popcll(kw_ & ((1ull << off) - 1ull));
            float* o = out + (((long)b * 2 + 1) * TOPK + pos) * 5;
            o[0] = bsc[tid];
            o[1] = bx1[tid];
            o[2] = by1[tid];
            o[3] = bx2[tid];
            o[4] = by2[tid];
        }
    }
}

extern "C" void kernel_launch(void* const* d_in, const int* in_sizes, int n_in,
                              void* d_out, int out_size, void* d_ws, size_t ws_size,
                              hipStream_t stream) {
    const float* loc   = (const float*)d_in[0];   // [64, 72192, 4]
    const float* conf  = (const float*)d_in[1];   // [64*72192, 2]
    const float* prior = (const float*)d_in[2];   // [72192, 4]
    float* out = (float*)d_out;                   // [64, 2, 200, 5]

    unsigned* ghist = (unsigned*)d_ws;                                  // 64*256 u32 = 65536 B
    unsigned* cnt   = ghist + BATCH * NBINS;                            // 64 u32  (ends 65792)
    unsigned long long* cand =
        (unsigned long long*)((char*)d_ws + 65792);                     // 64*1024 u64 = 512 KiB

    hipMemsetAsync(d_ws, 0, 65792, stream);

    hist_kernel<<<dim3(SLICES, BATCH), 256, 0, stream>>>(conf, ghist);
    collect_kernel<<<dim3(SLICES, BATCH), 256, 0, stream>>>(conf, ghist, cnt, cand);
    nms_kernel<<<BATCH, 256, 0, stream>>>(loc, prior, cnt, cand, out);
}

// Round 3
// 74.126 us; speedup vs baseline: 2.6021x; 1.9655x over previous
//
#include <hip/hip_runtime.h>
#include <math.h>

#pragma clang fp contract(off)

#define NUM_PRIORS 72192
#define BATCH      64
#define TOPK       200
#define CONF_TH    0.01f
#define NMS_TH     0.45f
#define NBINS      256
#define SLICES     32
#define ROWS       (NUM_PRIORS / SLICES)   // 2256
#define Q4         (ROWS / 2)              // 1128 float4 per slice
#define CAPS       64                      // candidate slots per slice segment
#define CAP        1024                    // max merged candidates in nms
#define SUPW       7                       // ceil(200/32)

typedef unsigned long long u64;

// ---- binning: monotonic map score -> bin, identical everywhere ----
__device__ __forceinline__ int bin_of(float s) {
    int b = (int)(s * 256.0f);
    return b > 255 ? 255 : b;
}

// ---------------- kernel 1: per-(batch,slice) histogram, plain stores ----------------
__global__ __launch_bounds__(256) void hist_kernel(const float* __restrict__ conf,
                                                   unsigned* __restrict__ shist) {
    __shared__ unsigned lhist[NBINS];
    const int b = blockIdx.y, slice = blockIdx.x, tid = threadIdx.x;
    lhist[tid] = 0;
    __syncthreads();
    const float4* c4 = (const float4*)conf;
    const long base4 = (long)b * (NUM_PRIORS / 2) + (long)slice * Q4;
    // 4 independent loads in flight (tid+768 <= 1023 < 1128 always valid)
    float4 v0 = c4[base4 + tid];
    float4 v1 = c4[base4 + tid + 256];
    float4 v2 = c4[base4 + tid + 512];
    float4 v3 = c4[base4 + tid + 768];
    if (v0.y > CONF_TH) atomicAdd(&lhist[bin_of(v0.y)], 1u);
    if (v0.w > CONF_TH) atomicAdd(&lhist[bin_of(v0.w)], 1u);
    if (v1.y > CONF_TH) atomicAdd(&lhist[bin_of(v1.y)], 1u);
    if (v1.w > CONF_TH) atomicAdd(&lhist[bin_of(v1.w)], 1u);
    if (v2.y > CONF_TH) atomicAdd(&lhist[bin_of(v2.y)], 1u);
    if (v2.w > CONF_TH) atomicAdd(&lhist[bin_of(v2.w)], 1u);
    if (v3.y > CONF_TH) atomicAdd(&lhist[bin_of(v3.y)], 1u);
    if (v3.w > CONF_TH) atomicAdd(&lhist[bin_of(v3.w)], 1u);
    if (tid < Q4 - 1024) {                 // tail: tid < 104
        float4 vt = c4[base4 + tid + 1024];
        if (vt.y > CONF_TH) atomicAdd(&lhist[bin_of(vt.y)], 1u);
        if (vt.w > CONF_TH) atomicAdd(&lhist[bin_of(vt.w)], 1u);
    }
    __syncthreads();
    shist[((long)b * SLICES + slice) * NBINS + tid] = lhist[tid];  // plain store
}

// ---------------- kernel 2: per-batch threshold bin ----------------
__global__ __launch_bounds__(256) void thresh_kernel(const unsigned* __restrict__ shist,
                                                     unsigned* __restrict__ Tarr) {
    __shared__ unsigned suf[NBINS];
    __shared__ int Tsh;
    const int b = blockIdx.x, tid = threadIdx.x;
    unsigned acc = 0;
    const unsigned* hb = shist + (long)b * SLICES * NBINS;
#pragma unroll
    for (int s = 0; s < SLICES; s++) acc += hb[s * NBINS + tid];   // coalesced per s
    suf[tid] = acc;
    if (tid == 0) Tsh = 0;
    __syncthreads();
    // suffix sum (Hillis-Steele)
    for (int off = 1; off < NBINS; off <<= 1) {
        unsigned v = (tid + off < NBINS) ? suf[tid + off] : 0u;
        __syncthreads();
        suf[tid] += v;
        __syncthreads();
    }
    unsigned s0 = suf[tid];
    unsigned sn = (tid + 1 < NBINS) ? suf[tid + 1] : 0u;
    if (s0 >= TOPK && (tid == NBINS - 1 || sn < TOPK)) Tsh = tid;
    __syncthreads();
    if (tid == 0) Tarr[b] = (unsigned)Tsh;  // if total < TOPK: stays 0 (take all)
}

// ---------------- kernel 3: collect survivors into private slice segments ----------------
__global__ __launch_bounds__(256) void collect_kernel(const float* __restrict__ conf,
                                                      const unsigned* __restrict__ Tarr,
                                                      unsigned* __restrict__ scnt,
                                                      u64* __restrict__ cand) {
    __shared__ unsigned lcnt;
    const int b = blockIdx.y, slice = blockIdx.x, tid = threadIdx.x;
    if (tid == 0) lcnt = 0;
    __syncthreads();
    const int T = (int)Tarr[b];
    const float4* c4 = (const float4*)conf;
    const long base4 = (long)b * (NUM_PRIORS / 2) + (long)slice * Q4;
    const int prow0 = slice * ROWS;
    u64* seg = cand + ((long)b * SLICES + slice) * CAPS;

    float4 v0 = c4[base4 + tid];
    float4 v1 = c4[base4 + tid + 256];
    float4 v2 = c4[base4 + tid + 512];
    float4 v3 = c4[base4 + tid + 768];

#define SLOT(sv, pidx)                                                          \
    do {                                                                        \
        float s_ = (sv);                                                        \
        if (s_ > CONF_TH && bin_of(s_) >= T) {                                  \
            unsigned pos = atomicAdd(&lcnt, 1u);   /* LDS atomic, rare */       \
            if (pos < CAPS)                                                     \
                seg[pos] = ((u64)__float_as_uint(s_) << 32) |                   \
                           (u64)(0xFFFFFFFFu - (unsigned)(pidx));               \
        }                                                                       \
    } while (0)

    SLOT(v0.y, prow0 + 2 * tid);
    SLOT(v0.w, prow0 + 2 * tid + 1);
    SLOT(v1.y, prow0 + 2 * (tid + 256));
    SLOT(v1.w, prow0 + 2 * (tid + 256) + 1);
    SLOT(v2.y, prow0 + 2 * (tid + 512));
    SLOT(v2.w, prow0 + 2 * (tid + 512) + 1);
    SLOT(v3.y, prow0 + 2 * (tid + 768));
    SLOT(v3.w, prow0 + 2 * (tid + 768) + 1);
    if (tid < Q4 - 1024) {
        float4 vt = c4[base4 + tid + 1024];
        SLOT(vt.y, prow0 + 2 * (tid + 1024));
        SLOT(vt.w, prow0 + 2 * (tid + 1024) + 1);
    }
#undef SLOT
    __syncthreads();
    if (tid == 0) {
        unsigned c = lcnt;
        scnt[b * SLICES + slice] = (c < CAPS) ? c : CAPS;   // plain store
    }
}

// ------- kernel 4: gather, rank-sort, decode, NMS (ballot greedy), compact, write -------
__global__ __launch_bounds__(256) void nms_kernel(const float* __restrict__ loc,
                           const float* __restrict__ prior,
                           const unsigned* __restrict__ scnt,
                           const u64* __restrict__ cand,
                           float* __restrict__ out) {
    __shared__ u64 keys[CAP];
    __shared__ int soff[SLICES + 1];
    __shared__ int scl[SLICES];
    __shared__ float bx1[TOPK], by1[TOPK], bx2[TOPK], by2[TOPK], bsc[TOPK], bar[TOPK];
    __shared__ unsigned supT[TOPK][SUPW];   // column-major: bit i of supT[j] = sup(i->j)
    __shared__ u64 keepw[4];
    __shared__ unsigned char vld[TOPK];
    const int b = blockIdx.x, tid = threadIdx.x;

    // zero this batch's output region (replaces host-side memset of d_out)
    {
        float* ob = out + (long)b * 2 * TOPK * 5;
        for (int i = tid; i < 2 * TOPK * 5; i += 256) ob[i] = 0.f;
    }
    if (tid < TOPK) {
        bsc[tid] = 0.f; bx1[tid] = 0.f; by1[tid] = 0.f; bx2[tid] = 0.f; by2[tid] = 0.f;
        bar[tid] = 0.f; vld[tid] = 0;
    }
    if (tid == 0) {
        int acc = 0;
        for (int s = 0; s < SLICES; s++) {
            soff[s] = acc;
            int cs = (int)scnt[b * SLICES + s];
            if (cs > CAPS) cs = CAPS;
            if (acc + cs > CAP) cs = CAP - acc;
            scl[s] = cs;
            acc += cs;
        }
        soff[SLICES] = acc;
    }
    __syncthreads();
    const int n = soff[SLICES];
    for (int pos = tid; pos < SLICES * CAPS; pos += 256) {
        int s = pos / CAPS, idx = pos % CAPS;
        if (idx < scl[s])
            keys[soff[s] + idx] = cand[((long)b * SLICES + s) * CAPS + idx];
    }
    __syncthreads();

    // ---- rank computation (exact top_k order: keys unique) + fused decode ----
    u64 kc[4];
#pragma unroll
    for (int s = 0; s < 4; s++) {
        int c = tid + s * 256;
        kc[s] = (c < n) ? keys[c] : 0ull;
    }
    int rk[4] = {0, 0, 0, 0};
    for (int k = 0; k < n; k++) {
        u64 kk = keys[k];   // broadcast read
#pragma unroll
        for (int s = 0; s < 4; s++) rk[s] += (kk > kc[s]) ? 1 : 0;
    }
#pragma unroll
    for (int s = 0; s < 4; s++) {
        int c = tid + s * 256;
        if (c < n && rk[s] < TOPK) {
            u64 key = kc[s];
            float sc = __uint_as_float((unsigned)(key >> 32));
            unsigned p = 0xFFFFFFFFu - (unsigned)(key & 0xFFFFFFFFull);
            float4 l4 = ((const float4*)loc)[(long)b * NUM_PRIORS + p];
            float4 p4 = ((const float4*)prior)[p];
            // match reference op order exactly (contract off)
            float cx = p4.x + (l4.x * 0.1f) * p4.z;
            float cy = p4.y + (l4.y * 0.1f) * p4.w;
            float w_ = p4.z * (float)exp((double)(l4.z * 0.2f));
            float h_ = p4.w * (float)exp((double)(l4.w * 0.2f));
            float x1 = cx - w_ * 0.5f, y1 = cy - h_ * 0.5f;
            float x2 = cx + w_ * 0.5f, y2 = cy + h_ * 0.5f;
            int r = rk[s];
            bsc[r] = sc; bx1[r] = x1; by1[r] = y1; bx2[r] = x2; by2[r] = y2;
            bar[r] = (x2 - x1) * (y2 - y1);
            vld[r] = 1;
        }
    }
    __syncthreads();

    // ---- build column-major suppression bitmask (thread j owns column j) ----
    if (tid < TOPK) {
        const int j = tid;
        const float jx1 = bx1[j], jy1 = by1[j], jx2 = bx2[j], jy2 = by2[j], jar = bar[j];
#pragma unroll
        for (int w = 0; w < SUPW; w++) {
            unsigned bits = 0u;
            const int nb = (w == 6) ? 8 : 32;
            for (int t = 0; t < nb; t++) {
                const int i = w * 32 + t;
                if (i < j) {
                    float ltx = fmaxf(bx1[i], jx1);
                    float lty = fmaxf(by1[i], jy1);
                    float rbx = fminf(bx2[i], jx2);
                    float rby = fminf(by2[i], jy2);
                    float wx = fmaxf(rbx - ltx, 0.0f);
                    float wy = fmaxf(rby - lty, 0.0f);
                    float inter = wx * wy;
                    float uni = (bar[i] + jar) - inter;
                    float iou = inter / fmaxf(uni, 1e-12f);
                    if (iou > NMS_TH) bits |= 1u << t;
                }
            }
            supT[j][w] = bits;
        }
    }
    __syncthreads();

    // ---- greedy resolve: wave 0, all-register, ballot-based (no LDS in loop) ----
    if (tid < 64) {
        const int l = tid;
        unsigned c0[SUPW], c1[SUPW], c2[SUPW], c3[SUPW];
#pragma unroll
        for (int w = 0; w < SUPW; w++) {
            c0[w] = supT[l][w];
            c1[w] = supT[l + 64][w];
            c2[w] = supT[l + 128][w];
            c3[w] = (l < 8) ? supT[l + 192][w] : 0u;
        }
        u64 k0 = __ballot(vld[l] != 0);
        u64 k1 = __ballot(vld[l + 64] != 0);
        u64 k2 = __ballot(vld[l + 128] != 0);
        u64 k3 = __ballot((l < 8) && (vld[l + 192] != 0));
#pragma unroll
        for (int w = 0; w < SUPW; w++) {
            const int nb = (w == 6) ? 8 : 32;
            for (int t = 0; t < nb; t++) {
                u64 m0 = __ballot(((c0[w] >> t) & 1u) != 0);
                u64 m1 = __ballot(((c1[w] >> t) & 1u) != 0);
                u64 m2 = __ballot(((c2[w] >> t) & 1u) != 0);
                u64 m3 = __ballot(((c3[w] >> t) & 1u) != 0);
                const int slot = w >> 1;                     // static per w
                u64 kw_ = (slot == 0) ? k0 : (slot == 1) ? k1
                         : (slot == 2) ? k2 : k3;
                bool ki = (kw_ >> ((w & 1) * 32 + t)) & 1ull;
                if (ki) { k0 &= ~m0; k1 &= ~m1; k2 &= ~m2; k3 &= ~m3; }
            }
        }
        if (l == 0) { keepw[0] = k0; keepw[1] = k1; keepw[2] = k2; keepw[3] = k3; }
    }
    __syncthreads();

    // ---- compact + write kept rows ----
    if (tid < TOPK) {
        const int slot = tid >> 6, off = tid & 63;
        const u64 kw_ = keepw[slot];
        if ((kw_ >> off) & 1ull) {
            int pos = 0;
            for (int s2 = 0; s2 < slot; s2++) pos += __popcll(keepw[s2]);
            pos += __popcll(kw_ & ((1ull << off) - 1ull));
            float* o = out + (((long)b * 2 + 1) * TOPK + pos) * 5;
            o[0] = bsc[tid];
            o[1] = bx1[tid];
            o[2] = by1[tid];
            o[3] = bx2[tid];
            o[4] = by2[tid];
        }
    }
}

extern "C" void kernel_launch(void* const* d_in, const int* in_sizes, int n_in,
                              void* d_out, int out_size, void* d_ws, size_t ws_size,
                              hipStream_t stream) {
    const float* loc   = (const float*)d_in[0];   // [64, 72192, 4]
    const float* conf  = (const float*)d_in[1];   // [64*72192, 2]
    const float* prior = (const float*)d_in[2];   // [72192, 4]
    float* out = (float*)d_out;                   // [64, 2, 200, 5]

    // ws layout (all regions fully written every launch -> no memset needed)
    unsigned* shist = (unsigned*)d_ws;                       // 64*32*256 u32 = 2 MiB
    unsigned* scnt  = shist + BATCH * SLICES * NBINS;        // 64*32 u32   = 8 KiB
    unsigned* Tarr  = scnt + BATCH * SLICES;                 // 64 u32
    u64* cand = (u64*)((char*)d_ws + 2105600);               // 64*32*64 u64 = 1 MiB (8B aligned)

    hist_kernel<<<dim3(SLICES, BATCH), 256, 0, stream>>>(conf, shist);
    thresh_kernel<<<BATCH, 256, 0, stream>>>(shist, Tarr);
    collect_kernel<<<dim3(SLICES, BATCH), 256, 0, stream>>>(conf, Tarr, scnt, cand);
    nms_kernel<<<BATCH, 256, 0, stream>>>(loc, prior, scnt, cand, out);
}

// Round 4
// 67.927 us; speedup vs baseline: 2.8395x; 1.0913x over previous
//
#include <hip/hip_runtime.h>
#include <math.h>

#pragma clang fp contract(off)

#define NUM_PRIORS 72192
#define BATCH      64
#define TOPK       200
#define CONF_TH    0.01f
#define NMS_TH     0.45f
#define NBINS      256
#define SLICES     32
#define ROWS       (NUM_PRIORS / SLICES)   // 2256
#define Q4         (ROWS / 2)              // 1128 float4 per slice
#define CAPS       64                      // candidate slots per slice segment
#define CAP        1024                    // max merged candidates in nms
#define SUPW       7                       // ceil(200/32)
#define NTH        512                     // nms block size (8 waves)

typedef unsigned long long u64;

// ---- binning: monotonic map score -> bin, identical everywhere ----
__device__ __forceinline__ int bin_of(float s) {
    int b = (int)(s * 256.0f);
    return b > 255 ? 255 : b;
}

// ---------------- kernel 1: per-(batch,slice) histogram, plain stores ----------------
__global__ __launch_bounds__(256) void hist_kernel(const float* __restrict__ conf,
                                                   unsigned* __restrict__ shist) {
    __shared__ unsigned lhist[NBINS];
    const int b = blockIdx.y, slice = blockIdx.x, tid = threadIdx.x;
    lhist[tid] = 0;
    __syncthreads();
    const float4* c4 = (const float4*)conf;
    const long base4 = (long)b * (NUM_PRIORS / 2) + (long)slice * Q4;
    float4 v0 = c4[base4 + tid];
    float4 v1 = c4[base4 + tid + 256];
    float4 v2 = c4[base4 + tid + 512];
    float4 v3 = c4[base4 + tid + 768];
    if (v0.y > CONF_TH) atomicAdd(&lhist[bin_of(v0.y)], 1u);
    if (v0.w > CONF_TH) atomicAdd(&lhist[bin_of(v0.w)], 1u);
    if (v1.y > CONF_TH) atomicAdd(&lhist[bin_of(v1.y)], 1u);
    if (v1.w > CONF_TH) atomicAdd(&lhist[bin_of(v1.w)], 1u);
    if (v2.y > CONF_TH) atomicAdd(&lhist[bin_of(v2.y)], 1u);
    if (v2.w > CONF_TH) atomicAdd(&lhist[bin_of(v2.w)], 1u);
    if (v3.y > CONF_TH) atomicAdd(&lhist[bin_of(v3.y)], 1u);
    if (v3.w > CONF_TH) atomicAdd(&lhist[bin_of(v3.w)], 1u);
    if (tid < Q4 - 1024) {
        float4 vt = c4[base4 + tid + 1024];
        if (vt.y > CONF_TH) atomicAdd(&lhist[bin_of(vt.y)], 1u);
        if (vt.w > CONF_TH) atomicAdd(&lhist[bin_of(vt.w)], 1u);
    }
    __syncthreads();
    shist[((long)b * SLICES + slice) * NBINS + tid] = lhist[tid];
}

// ---------------- kernel 2: per-batch threshold bin ----------------
__global__ __launch_bounds__(256) void thresh_kernel(const unsigned* __restrict__ shist,
                                                     unsigned* __restrict__ Tarr) {
    __shared__ unsigned suf[NBINS];
    __shared__ int Tsh;
    const int b = blockIdx.x, tid = threadIdx.x;
    unsigned acc = 0;
    const unsigned* hb = shist + (long)b * SLICES * NBINS;
#pragma unroll
    for (int s = 0; s < SLICES; s++) acc += hb[s * NBINS + tid];
    suf[tid] = acc;
    if (tid == 0) Tsh = 0;
    __syncthreads();
    for (int off = 1; off < NBINS; off <<= 1) {
        unsigned v = (tid + off < NBINS) ? suf[tid + off] : 0u;
        __syncthreads();
        suf[tid] += v;
        __syncthreads();
    }
    unsigned s0 = suf[tid];
    unsigned sn = (tid + 1 < NBINS) ? suf[tid + 1] : 0u;
    if (s0 >= TOPK && (tid == NBINS - 1 || sn < TOPK)) Tsh = tid;
    __syncthreads();
    if (tid == 0) Tarr[b] = (unsigned)Tsh;
}

// ---------------- kernel 3: collect survivors into private slice segments ----------------
__global__ __launch_bounds__(256) void collect_kernel(const float* __restrict__ conf,
                                                      const unsigned* __restrict__ Tarr,
                                                      unsigned* __restrict__ scnt,
                                                      u64* __restrict__ cand) {
    __shared__ unsigned lcnt;
    const int b = blockIdx.y, slice = blockIdx.x, tid = threadIdx.x;
    if (tid == 0) lcnt = 0;
    __syncthreads();
    const int T = (int)Tarr[b];
    const float4* c4 = (const float4*)conf;
    const long base4 = (long)b * (NUM_PRIORS / 2) + (long)slice * Q4;
    const int prow0 = slice * ROWS;
    u64* seg = cand + ((long)b * SLICES + slice) * CAPS;

    float4 v0 = c4[base4 + tid];
    float4 v1 = c4[base4 + tid + 256];
    float4 v2 = c4[base4 + tid + 512];
    float4 v3 = c4[base4 + tid + 768];

#define SLOT(sv, pidx)                                                          \
    do {                                                                        \
        float s_ = (sv);                                                        \
        if (s_ > CONF_TH && bin_of(s_) >= T) {                                  \
            unsigned pos = atomicAdd(&lcnt, 1u);                                \
            if (pos < CAPS)                                                     \
                seg[pos] = ((u64)__float_as_uint(s_) << 32) |                   \
                           (u64)(0xFFFFFFFFu - (unsigned)(pidx));               \
        }                                                                       \
    } while (0)

    SLOT(v0.y, prow0 + 2 * tid);
    SLOT(v0.w, prow0 + 2 * tid + 1);
    SLOT(v1.y, prow0 + 2 * (tid + 256));
    SLOT(v1.w, prow0 + 2 * (tid + 256) + 1);
    SLOT(v2.y, prow0 + 2 * (tid + 512));
    SLOT(v2.w, prow0 + 2 * (tid + 512) + 1);
    SLOT(v3.y, prow0 + 2 * (tid + 768));
    SLOT(v3.w, prow0 + 2 * (tid + 768) + 1);
    if (tid < Q4 - 1024) {
        float4 vt = c4[base4 + tid + 1024];
        SLOT(vt.y, prow0 + 2 * (tid + 1024));
        SLOT(vt.w, prow0 + 2 * (tid + 1024) + 1);
    }
#undef SLOT
    __syncthreads();
    if (tid == 0) {
        unsigned c = lcnt;
        scnt[b * SLICES + slice] = (c < CAPS) ? c : CAPS;
    }
}

// ------- kernel 4: gather, rank-sort, decode, NMS (ballot greedy), compact, write -------
__global__ __launch_bounds__(NTH) void nms_kernel(const float* __restrict__ loc,
                           const float* __restrict__ prior,
                           const unsigned* __restrict__ scnt,
                           const u64* __restrict__ cand,
                           float* __restrict__ out) {
    __shared__ u64 keys[CAP];
    __shared__ float4 bbox[TOPK];
    __shared__ float bar_s[TOPK], bsc_s[TOPK];
    __shared__ unsigned supT[TOPK][SUPW];   // column-major: bit i of supT[j] = sup(i->j)
    __shared__ u64 keepw[4];
    __shared__ unsigned char vld[TOPK];
    __shared__ int soff[SLICES + 1];
    __shared__ int scl[SLICES];
    const int b = blockIdx.x, tid = threadIdx.x;

    // wave 0: parallel slice-offset scan (1 coalesced load + shfl scan)
    if (tid < 64) {
        int s = tid;
        int c = 0;
        if (s < SLICES) {
            unsigned cs = scnt[b * SLICES + s];
            c = (cs < CAPS) ? (int)cs : CAPS;
        }
        int v = c;
#pragma unroll
        for (int d = 1; d < 32; d <<= 1) {
            int o = __shfl_up(v, d);
            if ((int)tid >= d) v += o;
        }
        if (s < SLICES) {
            int P = v - c;                         // exclusive prefix (untruncated)
            int off = P > CAP ? CAP : P;
            int rem = CAP - off;
            int cl = c < rem ? c : rem;
            soff[s] = off;
            scl[s] = cl;
            if (s == SLICES - 1) soff[SLICES] = (P + c > CAP) ? CAP : (P + c);
        }
    }
    // zero this batch's output region + LDS box state
    {
        float* ob = out + (long)b * 2 * TOPK * 5;
        for (int i = tid; i < 2 * TOPK * 5; i += NTH) ob[i] = 0.f;
    }
    if (tid < TOPK) {
        bsc_s[tid] = 0.f; bar_s[tid] = 0.f; vld[tid] = 0;
        bbox[tid] = make_float4(0.f, 0.f, 0.f, 0.f);
    }
    __syncthreads();

    const int n = soff[SLICES];
    const int nn = (n + 7) & ~7;
    for (int pos = tid; pos < SLICES * CAPS; pos += NTH) {
        int s = pos >> 6, idx = pos & 63;
        if (idx < scl[s])
            keys[soff[s] + idx] = cand[((long)b * SLICES + s) * CAPS + idx];
    }
    for (int i = n + tid; i < nn; i += NTH) keys[i] = 0ull;   // zero pad for unroll
    __syncthreads();

    // ---- rank computation (exact top_k order: keys unique), 8-deep unrolled ----
    u64 kc0 = (tid < n) ? keys[tid] : 0ull;
    u64 kc1 = (tid + NTH < n) ? keys[tid + NTH] : 0ull;
    int r0 = 0, r1 = 0;
    for (int k = 0; k < nn; k += 8) {
        u64 kb[8];
#pragma unroll
        for (int j = 0; j < 8; j++) kb[j] = keys[k + j];
#pragma unroll
        for (int j = 0; j < 8; j++) {
            r0 += (kb[j] > kc0) ? 1 : 0;
            r1 += (kb[j] > kc1) ? 1 : 0;
        }
    }
    // ---- fused decode of winners (identical float expressions to prior rounds) ----
#define DECODE(cidx, key, r)                                                    \
    do {                                                                        \
        if ((cidx) < n && (r) < TOPK) {                                         \
            float sc = __uint_as_float((unsigned)((key) >> 32));                \
            unsigned p = 0xFFFFFFFFu - (unsigned)((key) & 0xFFFFFFFFull);       \
            float4 l4 = ((const float4*)loc)[(long)b * NUM_PRIORS + p];         \
            float4 p4 = ((const float4*)prior)[p];                              \
            float cx = p4.x + (l4.x * 0.1f) * p4.z;                             \
            float cy = p4.y + (l4.y * 0.1f) * p4.w;                             \
            float w_ = p4.z * (float)exp((double)(l4.z * 0.2f));                \
            float h_ = p4.w * (float)exp((double)(l4.w * 0.2f));                \
            float x1 = cx - w_ * 0.5f, y1 = cy - h_ * 0.5f;                     \
            float x2 = cx + w_ * 0.5f, y2 = cy + h_ * 0.5f;                     \
            bsc_s[r] = sc;                                                      \
            bbox[r] = make_float4(x1, y1, x2, y2);                              \
            bar_s[r] = (x2 - x1) * (y2 - y1);                                   \
            vld[r] = 1;                                                         \
        }                                                                       \
    } while (0)
    DECODE(tid, kc0, r0);
    DECODE(tid + NTH, kc1, r1);
#undef DECODE
    __syncthreads();

    // ---- build column-major suppression bitmask (thread j owns column j) ----
    if (tid < TOPK) {
        const int j = tid;
        const float4 jb = bbox[j];
        const float jar = bar_s[j];
#pragma unroll
        for (int w = 0; w < SUPW; w++) {
            unsigned bits = 0u;
            const int nb = (w == 6) ? 8 : 32;
#pragma unroll
            for (int t = 0; t < nb; t++) {
                const int i = w * 32 + t;
                if (i < j) {
                    float4 ib = bbox[i];          // ds_read_b128 broadcast
                    float ltx = fmaxf(ib.x, jb.x);
                    float lty = fmaxf(ib.y, jb.y);
                    float rbx = fminf(ib.z, jb.z);
                    float rby = fminf(ib.w, jb.w);
                    float wx = fmaxf(rbx - ltx, 0.0f);
                    float wy = fmaxf(rby - lty, 0.0f);
                    float inter = wx * wy;
                    float uni = (bar_s[i] + jar) - inter;
                    float iou = inter / fmaxf(uni, 1e-12f);
                    if (iou > NMS_TH) bits |= 1u << t;
                }
            }
            supT[j][w] = bits;
        }
    }
    __syncthreads();

    // ---- greedy resolve: wave 0, all-register, ballot-based (no LDS in loop) ----
    if (tid < 64) {
        const int l = tid;
        unsigned c0[SUPW], c1[SUPW], c2[SUPW], c3[SUPW];
#pragma unroll
        for (int w = 0; w < SUPW; w++) {
            c0[w] = supT[l][w];
            c1[w] = supT[l + 64][w];
            c2[w] = supT[l + 128][w];
            c3[w] = (l < 8) ? supT[l + 192][w] : 0u;
        }
        u64 k0 = __ballot(vld[l] != 0);
        u64 k1 = __ballot(vld[l + 64] != 0);
        u64 k2 = __ballot(vld[l + 128] != 0);
        u64 k3 = __ballot((l < 8) && (vld[l + 192] != 0));
#pragma unroll
        for (int w = 0; w < SUPW; w++) {
            const int nb = (w == 6) ? 8 : 32;
            for (int t = 0; t < nb; t++) {
                u64 m0 = __ballot(((c0[w] >> t) & 1u) != 0);
                u64 m1 = __ballot(((c1[w] >> t) & 1u) != 0);
                u64 m2 = __ballot(((c2[w] >> t) & 1u) != 0);
                u64 m3 = __ballot(((c3[w] >> t) & 1u) != 0);
                const int slot = w >> 1;
                u64 kw_ = (slot == 0) ? k0 : (slot == 1) ? k1
                         : (slot == 2) ? k2 : k3;
                bool ki = (kw_ >> ((w & 1) * 32 + t)) & 1ull;
                if (ki) { k0 &= ~m0; k1 &= ~m1; k2 &= ~m2; k3 &= ~m3; }
            }
        }
        if (l == 0) { keepw[0] = k0; keepw[1] = k1; keepw[2] = k2; keepw[3] = k3; }
    }
    __syncthreads();

    // ---- compact + write kept rows ----
    if (tid < TOPK) {
        const int slot = tid >> 6, off = tid & 63;
        const u64 kw_ = keepw[slot];
        if ((kw_ >> off) & 1ull) {
            int pos = 0;
            for (int s2 = 0; s2 < slot; s2++) pos += __popcll(keepw[s2]);
            pos += __popcll(kw_ & ((1ull << off) - 1ull));
            float4 jb = bbox[tid];
            float* o = out + (((long)b * 2 + 1) * TOPK + pos) * 5;
            o[0] = bsc_s[tid];
            o[1] = jb.x;
            o[2] = jb.y;
            o[3] = jb.z;
            o[4] = jb.w;
        }
    }
}

extern "C" void kernel_launch(void* const* d_in, const int* in_sizes, int n_in,
                              void* d_out, int out_size, void* d_ws, size_t ws_size,
                              hipStream_t stream) {
    const float* loc   = (const float*)d_in[0];   // [64, 72192, 4]
    const float* conf  = (const float*)d_in[1];   // [64*72192, 2]
    const float* prior = (const float*)d_in[2];   // [72192, 4]
    float* out = (float*)d_out;                   // [64, 2, 200, 5]

    // ws layout (all regions fully written every launch -> no memset needed)
    unsigned* shist = (unsigned*)d_ws;                       // 64*32*256 u32 = 2 MiB
    unsigned* scnt  = shist + BATCH * SLICES * NBINS;        // 64*32 u32   = 8 KiB
    unsigned* Tarr  = scnt + BATCH * SLICES;                 // 64 u32
    u64* cand = (u64*)((char*)d_ws + 2105600);               // 64*32*64 u64 = 1 MiB (8B aligned)

    hist_kernel<<<dim3(SLICES, BATCH), 256, 0, stream>>>(conf, shist);
    thresh_kernel<<<BATCH, 256, 0, stream>>>(shist, Tarr);
    collect_kernel<<<dim3(SLICES, BATCH), 256, 0, stream>>>(conf, Tarr, scnt, cand);
    nms_kernel<<<NTH == 512 ? BATCH : BATCH, NTH, 0, stream>>>(loc, prior, scnt, cand, out);
}